// Round 4
// baseline (116.476 us; speedup 1.0000x reference)
//
#include <hip/hip_runtime.h>
#include <hip/hip_bf16.h>

// Problem constants (from reference)
#define NB   2
#define CC   10
#define HH   30
#define WW   30
#define PADR 4
#define DD   11     // C+1
#define LL   100    // MAXH*MAXW
#define BPIX (NB*HH*WW)   // 1800 sequences / pixels

__device__ __forceinline__ float b2f(__hip_bfloat16 v) { return __bfloat162float(v); }

// Runtime-dtype input loader (flag from per-buffer probe).
__device__ __forceinline__ float ldin(const void* p, int i, bool is_bf16) {
    return is_bf16 ? b2f(((const __hip_bfloat16*)p)[i])
                   : ((const float*)p)[i];
}

// Statistical dtype probe for a random-normal (0.1*N) weight buffer.
// Read as bf16: true-bf16 -> nearly all values "sane"; f32-as-bf16 -> only
// odd indices (f32 high halves) sane (~50%). Reads stay in-bounds under
// both interpretations (2n bytes <= f32 byte size).
__device__ __forceinline__ bool probe_bf16(const void* p, int n, int thresh) {
    const __hip_bfloat16* q = (const __hip_bfloat16*)p;
    int sane = 0;
    for (int i = 0; i < n; i++) {
        const float a = fabsf(b2f(q[i]));
        if (a == 0.f || (a > 1e-4f && a < 4.f)) sane++;
    }
    return sane >= thresh;
}

// One block per pixel b = (n,i,j). 128 threads.
// seq rows are one-hot -> q/k/v are columns of w_in selected by per-cell
// class ch in {0..10}; per-channel softmax-attention reduces to a class-
// histogram weighted sum; only the ch==10 (indicator) query produces a
// non-trivial output (mask0 zeroes 'colored' for in-image tokens, and
// all-zero padded slots output 0 -- their uniform-attention h is killed
// by mask0 as well).
__global__ __launch_bounds__(128) void pve_fused(
    const void* __restrict__ x,      // (N,C,H,W) one-hot
    const void* __restrict__ w_in,   // (33,11)
    const void* __restrict__ w_out,  // (11,11)
    const void* __restrict__ w_ff1,  // (1,11)
    const void* __restrict__ w_ff2,  // (11,1)
    const void* __restrict__ ln1g,   // (11,) == ones
    const void* __restrict__ ln2g,   // (11,) == ones
    float* __restrict__ out)         // (1800,10,100) float32
{
    __shared__ float E[121];    // exp(Q[d]*K[d][c]), Q = w_in[d][10]
    __shared__ float EV[121];   // E * V[d][c]
    __shared__ float WO[121];   // w_out fp32
    __shared__ float G1[11], G2[11], F1[11], F2[11];
    __shared__ int   ch[LL];    // per-slot class (-1 invalid, 10 indicator)
    __shared__ int   cnt[11];   // window class histogram
    __shared__ float ao[11];
    __shared__ float stA[11];
    __shared__ float stB[11];
    __shared__ float smv[10];   // final softmax (indicator query)
    __shared__ bool  fB[7];     // per-buffer "is bf16" flags

    const int t = threadIdx.x;
    const int b = blockIdx.x;
    const int n  = b / (HH * WW);
    const int rm = b % (HH * WW);
    const int i0 = rm / WW;
    const int j0 = rm % WW;

    // ---- stage -1: per-buffer dtype probes (thread 0) ----
    if (t == 0) {
        // x: one-hot over channel k at pixel (0,0,0). bf16 -> sum == 1.0
        // exactly; f32 -> every even-position bf16 read is a low16 of
        // {0.0f,1.0f} == 0x0000 -> sum == 0.
        float s = 0.f;
        for (int k = 0; k < CC; k++)
            s += fabsf(b2f(((const __hip_bfloat16*)x)[k * HH * WW]));
        fB[0] = (s > 0.5f);
        fB[1] = probe_bf16(w_in, 363, 300);
        fB[2] = probe_bf16(w_out, 121, 100);
        fB[3] = probe_bf16(w_ff1, 11, 9);
        fB[4] = probe_bf16(w_ff2, 11, 9);
        // ln gains are exactly ones: dword0 0x3F800000 (f32) / 0x3F803F80 (bf16)
        fB[5] = (*(const unsigned int*)ln1g) != 0x3F800000u;
        fB[6] = (*(const unsigned int*)ln2g) != 0x3F800000u;
    }
    __syncthreads();
    const bool fx  = fB[0], fwi = fB[1], fwo = fB[2], ff1 = fB[3],
               ff2 = fB[4], fg1 = fB[5], fg2 = fB[6];

    // ---- stage 0: input-independent tables ----
    if (t < 121) {
        const int d = t / 11, c = t % 11;
        const float Q = ldin(w_in, d * DD + 10, fwi);
        const float K = ldin(w_in, (DD + d) * DD + c, fwi);
        const float V = ldin(w_in, (2 * DD + d) * DD + c, fwi);
        float arg = Q * K;
        arg = fminf(fmaxf(arg, -30.f), 30.f);   // never binds on real data
        const float e = __expf(arg);
        E[t] = e;
        EV[t] = e * V;
        WO[t] = ldin(w_out, t, fwo);
    }
    if (t < 11) {
        G1[t] = ldin(ln1g, t, fg1);
        G2[t] = ldin(ln2g, t, fg2);
        F1[t] = ldin(w_ff1, t, ff1);   // w_ff1 is (1,11) -> flat
        F2[t] = ldin(w_ff2, t, ff2);   // w_ff2 is (11,1) -> flat
        cnt[t] = 0;
    }
    __syncthreads();

    // ---- stage 1: per-slot class + histogram ----
    if (t < LL) {
        const int ph = t / 10, pw = t % 10;
        int c = -1;                       // invalid slot (ph>=9 || pw>=9)
        if (ph < 9 && pw < 9) {
            const int r  = i0 + ph - PADR;
            const int cc = j0 + pw - PADR;
            if (r < 0 || r >= HH || cc < 0 || cc >= WW) {
                c = 10;                   // out-of-image -> indicator class
            } else {
                const int base = n * CC * HH * WW + r * WW + cc;
                c = 10;                   // fallback (never hit: exact one-hot)
                #pragma unroll
                for (int k = 0; k < CC; k++) {
                    if (ldin(x, base + k * HH * WW, fx) > 0.5f) { c = k; break; }
                }
            }
            atomicAdd(&cnt[c], 1);
        }
        ch[t] = c;
    }
    __syncthreads();

    // ---- stage 2: per-channel softmax-attention via histogram ----
    if (t < 11) {
        float s1 = 0.f, s2 = 0.f;
        #pragma unroll
        for (int c = 0; c < 11; c++) {
            const float cn = (float)cnt[c];
            s1 += cn * E[t * 11 + c];
            s2 += cn * EV[t * 11 + c];
        }
        ao[t] = s2 / s1;
    }
    __syncthreads();

    // ---- stage 3: ao @ w_out.T + e_10 residual ----
    if (t < 11) {
        float v = 0.f;
        #pragma unroll
        for (int j = 0; j < 11; j++) v += WO[t * 11 + j] * ao[j];
        if (t == 10) v += 1.0f;
        stA[t] = v;
    }
    __syncthreads();

    // ---- stage 4: LN1 ----
    if (t < 11) {
        float m = 0.f;
        #pragma unroll
        for (int j = 0; j < 11; j++) m += stA[j];
        m *= (1.f / 11.f);
        float var = 0.f;
        #pragma unroll
        for (int j = 0; j < 11; j++) { const float d = stA[j] - m; var += d * d; }
        var *= (1.f / 11.f);
        stB[t] = (stA[t] - m) * rsqrtf(var + 1e-5f) * G1[t];
    }
    __syncthreads();

    // ---- stage 5: FF (scalar bottleneck) + residual ----
    if (t < 11) {
        float s = 0.f;
        #pragma unroll
        for (int j = 0; j < 11; j++) s += stB[j] * F1[j];
        s = fmaxf(s, 0.f);
        stA[t] = stB[t] + s * F2[t];
    }
    __syncthreads();

    // ---- stage 6: LN2 ----
    if (t < 11) {
        float m = 0.f;
        #pragma unroll
        for (int j = 0; j < 11; j++) m += stA[j];
        m *= (1.f / 11.f);
        float var = 0.f;
        #pragma unroll
        for (int j = 0; j < 11; j++) { const float d = stA[j] - m; var += d * d; }
        var *= (1.f / 11.f);
        stB[t] = (stA[t] - m) * rsqrtf(var + 1e-5f) * G2[t];
    }
    __syncthreads();

    // ---- stage 7: softmax over first 10 channels (indicator query) ----
    if (t < 10) {
        float mx = -1e30f;
        #pragma unroll
        for (int j = 0; j < 10; j++) mx = fmaxf(mx, stB[j]);
        float den = 0.f;
        #pragma unroll
        for (int j = 0; j < 10; j++) den += __expf(stB[j] - mx);
        smv[t] = __expf(stB[t] - mx) / den;
    }
    __syncthreads();

    // ---- stage 8: write 1000 FLOAT32 outputs for this pixel ----
    // out[b, c, l]: invalid slot -> 0; class cl<10 -> one-hot; cl==10 -> smv.
    // 1000 f32 = 250 x float4 (16B); chunk base b*4000 bytes is 16B-aligned;
    // a float4 never crosses a c boundary (4 | 100).
    for (int vi = t; vi < 250; vi += 128) {
        const int idx = vi * 4;
        const int c = idx / 100;
        const int l0 = idx - c * 100;
        float4 v4;
        float* pv = &v4.x;
        #pragma unroll
        for (int q = 0; q < 4; q++) {
            const int cl = ch[l0 + q];
            float v;
            if (cl < 0)        v = 0.f;
            else if (cl < 10)  v = (c == cl) ? 1.f : 0.f;
            else               v = smv[c];
            pv[q] = v;
        }
        reinterpret_cast<float4*>(out + (size_t)b * 1000)[vi] = v4;
    }
}

extern "C" void kernel_launch(void* const* d_in, const int* in_sizes, int n_in,
                              void* d_out, int out_size, void* d_ws, size_t ws_size,
                              hipStream_t stream) {
    pve_fused<<<BPIX, 128, 0, stream>>>(d_in[0], d_in[1], d_in[2], d_in[3],
                                        d_in[4], d_in[5], d_in[6],
                                        (float*)d_out);
}

// Round 5
// 80.179 us; speedup vs baseline: 1.4527x; 1.4527x over previous
//
#include <hip/hip_runtime.h>

// Problem constants (from reference)
#define NB   2
#define CC   10
#define HH   30
#define WW   30
#define PADR 4
#define DD   11       // C+1
#define NPIX (NB*HH*WW)   // 1800 pixels
#define GP   16       // lanes per pixel group
#define PPB  4        // pixels per 64-thread block
#define NBLK (NPIX/PPB)   // 450, exact

// ---------------- Kernel 1: one-hot x -> class map (uchar per pixel) --------
__global__ __launch_bounds__(256) void classify(const float* __restrict__ x,
                                                unsigned char* __restrict__ cm) {
    const int p = blockIdx.x * 256 + threadIdx.x;
    if (p >= NPIX) return;
    const int n  = p / (HH * WW);
    const int rm = p % (HH * WW);
    const float* xp = x + n * CC * HH * WW + rm;   // stride HW per channel
    int c = 10;                                     // never hit: exact one-hot
    #pragma unroll
    for (int k = 0; k < CC; k++) {
        if (xp[k * HH * WW] > 0.5f) { c = k; break; }
    }
    cm[p] = (unsigned char)c;
}

// ---------------- Kernel 2: per-pixel pipeline + output ---------------------
// 16 lanes per pixel; whole pipeline wave-synchronous via shfl (width 16).
// seq rows are one-hot -> per-channel softmax-attention reduces to a class-
// histogram weighted sum over tables E/EV; only the indicator-query (class
// 10) output is non-trivial; others are one-hot / zero (validated: absmax 0).
__global__ __launch_bounds__(64) void emit(
    const float* __restrict__ w_in,   // (33,11)
    const float* __restrict__ w_out,  // (11,11)
    const float* __restrict__ w_ff1,  // (1,11)
    const float* __restrict__ w_ff2,  // (11,1)
    const float* __restrict__ ln1g,   // (11,)
    const float* __restrict__ ln2g,   // (11,)
    const unsigned char* __restrict__ cm,  // (1800,) class map
    float* __restrict__ out)          // (1800,10,100) f32
{
    __shared__ float E[121];    // exp(Q[d]*K[d][c]), Q = w_in[d][10]
    __shared__ float EV[121];   // E * V[d][c]
    __shared__ float WO[121];
    __shared__ float G1[11], G2[11], F1[11], F2[11];
    __shared__ unsigned char chs[PPB][100];   // per-pixel slot classes

    const int t = threadIdx.x;

    // tables (lanes cooperate; visible after the single __syncthreads below)
    for (int i = t; i < 121; i += 64) {
        const int d = i / 11, c = i % 11;
        const float Q = w_in[d * DD + 10];
        const float K = w_in[(DD + d) * DD + c];
        const float V = w_in[(2 * DD + d) * DD + c];
        const float e = __expf(Q * K);
        E[i] = e; EV[i] = e * V; WO[i] = w_out[i];
    }
    if (t < 11) { G1[t] = ln1g[t]; G2[t] = ln2g[t]; F1[t] = w_ff1[t]; F2[t] = w_ff2[t]; }

    const int grp = t >> 4;          // 0..3  (pixel within block)
    const int g   = t & 15;          // lane within group
    const int pix = blockIdx.x * PPB + grp;   // < 1800 exactly (450*4)
    const int n  = pix / (HH * WW);
    const int rm = pix % (HH * WW);
    const int i0 = rm / WW, j0 = rm % WW;

    // ---- phase 1: slot classes (l = ph*10+pw) + byte-packed local histogram
    unsigned int pk0 = 0, pk1 = 0, pk2 = 0;   // classes 0-3 / 4-7 / 8-10
    for (int l = g; l < 100; l += GP) {
        const int ph = l / 10, pw = l % 10;
        unsigned int c = 255;                 // invalid slot
        if (ph < 9 && pw < 9) {
            const int r  = i0 + ph - PADR;
            const int cc = j0 + pw - PADR;
            c = 10;                           // border indicator
            if (r >= 0 && r < HH && cc >= 0 && cc < WW)
                c = cm[n * HH * WW + r * WW + cc];
            const unsigned int inc = 1u << ((c & 3) * 8);
            if (c < 4) pk0 += inc; else if (c < 8) pk1 += inc; else pk2 += inc;
        }
        chs[grp][l] = (unsigned char)c;
    }
    __syncthreads();   // tables + chs visible (single barrier in kernel)

    // ---- histogram reduce across the 16-lane group (counts <= 81 per byte)
    #pragma unroll
    for (int m = 1; m < GP; m <<= 1) {
        pk0 += __shfl_xor(pk0, m, GP);
        pk1 += __shfl_xor(pk1, m, GP);
        pk2 += __shfl_xor(pk2, m, GP);
    }
    float cnt[11];
    #pragma unroll
    for (int c = 0; c < 11; c++) {
        const unsigned int pk = (c < 4) ? pk0 : ((c < 8) ? pk1 : pk2);
        cnt[c] = (float)((pk >> ((c & 3) * 8)) & 0xFFu);
    }

    const int d = (g < 11) ? g : 0;   // lanes 11-15 compute garbage, masked

    // ---- attention via histogram: ao[d] = sum(cnt*EV) / sum(cnt*E)
    float s1 = 0.f, s2 = 0.f;
    #pragma unroll
    for (int c = 0; c < 11; c++) {
        s1 += cnt[c] * E[d * 11 + c];
        s2 += cnt[c] * EV[d * 11 + c];
    }
    const float ao = s2 / s1;

    // ---- ao @ w_out.T + e_10 residual
    float h = 0.f;
    #pragma unroll
    for (int j = 0; j < 11; j++)
        h += WO[d * 11 + j] * __shfl(ao, j, GP);
    if (g == 10) h += 1.0f;
    if (g >= 11) h = 0.f;

    // ---- LN1 (two-pass, group reductions via shfl_xor)
    float s = h;
    #pragma unroll
    for (int m = 1; m < GP; m <<= 1) s += __shfl_xor(s, m, GP);
    float mean = s * (1.f / 11.f);
    float dv = (g < 11) ? (h - mean) : 0.f;
    float sq = dv * dv;
    #pragma unroll
    for (int m = 1; m < GP; m <<= 1) sq += __shfl_xor(sq, m, GP);
    const float hb = dv * rsqrtf(sq * (1.f / 11.f) + 1e-5f) * G1[d]; // 0 for g>=11

    // ---- FF (scalar bottleneck) + residual
    float f = hb * F1[d];
    #pragma unroll
    for (int m = 1; m < GP; m <<= 1) f += __shfl_xor(f, m, GP);
    f = fmaxf(f, 0.f);
    float h2 = hb + f * F2[d];
    if (g >= 11) h2 = 0.f;

    // ---- LN2
    s = h2;
    #pragma unroll
    for (int m = 1; m < GP; m <<= 1) s += __shfl_xor(s, m, GP);
    mean = s * (1.f / 11.f);
    dv = (g < 11) ? (h2 - mean) : 0.f;
    sq = dv * dv;
    #pragma unroll
    for (int m = 1; m < GP; m <<= 1) sq += __shfl_xor(sq, m, GP);
    const float hc = dv * rsqrtf(sq * (1.f / 11.f) + 1e-5f) * G2[d];

    // ---- softmax over channels 0..9 (indicator query)
    float mv = (g < 10) ? hc : -1e30f;
    #pragma unroll
    for (int m = 1; m < GP; m <<= 1) mv = fmaxf(mv, __shfl_xor(mv, m, GP));
    const float ex = (g < 10) ? __expf(hc - mv) : 0.f;
    float den = ex;
    #pragma unroll
    for (int m = 1; m < GP; m <<= 1) den += __shfl_xor(den, m, GP);
    const float smv = ex / den;   // valid on lanes g<10

    // ---- epilogue: 1000 f32 per pixel = 250 float4, coalesced per group.
    // out[pix, c, l]: invalid -> 0; class cl<10 -> one-hot; cl==10 -> smv[c].
    float* po = out + (size_t)pix * 1000;
    const unsigned char* chp = chs[grp];
    for (int vi = g; vi < 250; vi += GP) {
        const int idx = vi * 4;
        const int c   = idx / 100;          // 0..9, constant within float4
        const int l0  = idx - c * 100;      // multiple of 4
        const uchar4 c4 = *reinterpret_cast<const uchar4*>(chp + l0);
        const float sv = __shfl(smv, c, GP);
        float4 v4;
        v4.x = (c4.x == 255) ? 0.f : ((c4.x < 10) ? ((c == c4.x) ? 1.f : 0.f) : sv);
        v4.y = (c4.y == 255) ? 0.f : ((c4.y < 10) ? ((c == c4.y) ? 1.f : 0.f) : sv);
        v4.z = (c4.z == 255) ? 0.f : ((c4.z < 10) ? ((c == c4.z) ? 1.f : 0.f) : sv);
        v4.w = (c4.w == 255) ? 0.f : ((c4.w < 10) ? ((c == c4.w) ? 1.f : 0.f) : sv);
        reinterpret_cast<float4*>(po)[vi] = v4;
    }
}

extern "C" void kernel_launch(void* const* d_in, const int* in_sizes, int n_in,
                              void* d_out, int out_size, void* d_ws, size_t ws_size,
                              hipStream_t stream) {
    const float* x     = (const float*)d_in[0];
    const float* w_in  = (const float*)d_in[1];
    const float* w_out = (const float*)d_in[2];
    const float* w_ff1 = (const float*)d_in[3];
    const float* w_ff2 = (const float*)d_in[4];
    const float* ln1g  = (const float*)d_in[5];
    const float* ln2g  = (const float*)d_in[6];
    unsigned char* cm  = (unsigned char*)d_ws;   // 1800 bytes
    float* out = (float*)d_out;

    classify<<<(NPIX + 255) / 256, 256, 0, stream>>>(x, cm);
    emit<<<NBLK, 64, 0, stream>>>(w_in, w_out, w_ff1, w_ff2, ln1g, ln2g, cm, out);
}

// Round 6
// 76.858 us; speedup vs baseline: 1.5155x; 1.0432x over previous
//
#include <hip/hip_runtime.h>

// Problem constants (from reference)
#define NB   2
#define CC   10
#define HH   30
#define WW   30
#define PADR 4
#define DD   11           // C+1
#define NPIX (NB*HH*WW)   // 1800 pixels

// ---------------- Kernel 1: one-hot x -> class map (uchar per pixel) --------
__global__ __launch_bounds__(256) void classify(const float* __restrict__ x,
                                                unsigned char* __restrict__ cm) {
    const int p = blockIdx.x * 256 + threadIdx.x;
    if (p >= NPIX) return;
    const int n  = p / (HH * WW);
    const int rm = p % (HH * WW);
    const float* xp = x + n * CC * HH * WW + rm;   // stride HW per channel
    int c = 10;                                     // never hit: exact one-hot
    #pragma unroll
    for (int k = 0; k < CC; k++) {
        if (xp[k * HH * WW] > 0.5f) { c = k; break; }
    }
    cm[p] = (unsigned char)c;
}

// ---------------- Kernel 2: one block (128 thr) per pixel -------------------
// seq rows are one-hot -> per-channel softmax-attention reduces to a class-
// histogram weighted sum over tables E/EV; only the indicator-query (class
// 10) output is non-trivial (validated bit-exact in R4/R5).
// Phase A: 100 threads decode window slots + LDS-atomic histogram.
// Phase B: lanes 0-15 run the 11-dim pipeline wave-synchronously (shfl w16).
// Phase C: all 128 lanes emit 250 coalesced float4 (2 per lane).
__global__ __launch_bounds__(128) void emit(
    const float* __restrict__ w_in,   // (33,11)
    const float* __restrict__ w_out,  // (11,11)
    const float* __restrict__ w_ff1,  // (1,11)
    const float* __restrict__ w_ff2,  // (11,1)
    const float* __restrict__ ln1g,   // (11,)
    const float* __restrict__ ln2g,   // (11,)
    const unsigned char* __restrict__ cm,  // (1800,) class map
    float* __restrict__ out)          // (1800,10,100) f32
{
    __shared__ float E[121];    // exp(Q[d]*K[d][c]), Q = w_in[d][10]
    __shared__ float EV[121];   // E * V[d][c]
    __shared__ float WO[121];
    __shared__ float G1[11], G2[11], F1[11], F2[11];
    __shared__ int   cnt[11];
    __shared__ float smvS[10];
    __shared__ unsigned char chs[100];  // slot classes (255 = invalid)

    const int t = threadIdx.x;
    const int pix = blockIdx.x;
    const int n  = pix / (HH * WW);
    const int rm = pix % (HH * WW);
    const int i0 = rm / WW, j0 = rm % WW;

    // ---- tables (one pass over 128 threads) ----
    if (t < 121) {
        const int d = t / 11, c = t % 11;
        const float Q = w_in[d * DD + 10];
        const float K = w_in[(DD + d) * DD + c];
        const float V = w_in[(2 * DD + d) * DD + c];
        const float e = __expf(Q * K);
        E[t] = e; EV[t] = e * V; WO[t] = w_out[t];
    }
    if (t < 11) {
        G1[t] = ln1g[t]; G2[t] = ln2g[t];
        F1[t] = w_ff1[t]; F2[t] = w_ff2[t];
        cnt[t] = 0;
    }
    __syncthreads();

    // ---- phase A: slot classes + histogram (t < 100), l = ph*10+pw ----
    if (t < 100) {
        const int ph = t / 10, pw = t % 10;
        unsigned int c = 255;                 // invalid slot
        if (ph < 9 && pw < 9) {
            const int r  = i0 + ph - PADR;
            const int cc = j0 + pw - PADR;
            c = 10;                           // border indicator
            if (r >= 0 && r < HH && cc >= 0 && cc < WW)
                c = cm[n * HH * WW + r * WW + cc];
            atomicAdd(&cnt[c], 1);
        }
        chs[t] = (unsigned char)c;
    }
    __syncthreads();

    // ---- phase B: 11-dim pipeline on lanes 0-15 (wave-synchronous) ----
    if (t < 16) {
        const int g = t;
        const int d = (g < 11) ? g : 0;

        // attention via histogram: ao[d] = sum(cnt*EV)/sum(cnt*E)
        float s1 = 0.f, s2 = 0.f;
        #pragma unroll
        for (int c = 0; c < 11; c++) {
            const float cn = (float)cnt[c];
            s1 += cn * E[d * 11 + c];
            s2 += cn * EV[d * 11 + c];
        }
        const float ao = s2 / s1;

        // ao @ w_out.T + e_10 residual
        float h = 0.f;
        #pragma unroll
        for (int j = 0; j < 11; j++)
            h += WO[d * 11 + j] * __shfl(ao, j, 16);
        if (g == 10) h += 1.0f;
        if (g >= 11) h = 0.f;

        // LN1
        float s = h;
        #pragma unroll
        for (int m = 1; m < 16; m <<= 1) s += __shfl_xor(s, m, 16);
        float mean = s * (1.f / 11.f);
        float dv = (g < 11) ? (h - mean) : 0.f;
        float sq = dv * dv;
        #pragma unroll
        for (int m = 1; m < 16; m <<= 1) sq += __shfl_xor(sq, m, 16);
        const float hb = dv * rsqrtf(sq * (1.f / 11.f) + 1e-5f) * G1[d];

        // FF (scalar bottleneck) + residual
        float f = hb * F1[d];
        #pragma unroll
        for (int m = 1; m < 16; m <<= 1) f += __shfl_xor(f, m, 16);
        f = fmaxf(f, 0.f);
        float h2 = hb + f * F2[d];
        if (g >= 11) h2 = 0.f;

        // LN2
        s = h2;
        #pragma unroll
        for (int m = 1; m < 16; m <<= 1) s += __shfl_xor(s, m, 16);
        mean = s * (1.f / 11.f);
        dv = (g < 11) ? (h2 - mean) : 0.f;
        sq = dv * dv;
        #pragma unroll
        for (int m = 1; m < 16; m <<= 1) sq += __shfl_xor(sq, m, 16);
        const float hc = dv * rsqrtf(sq * (1.f / 11.f) + 1e-5f) * G2[d];

        // softmax over channels 0..9 (indicator query)
        float mv = (g < 10) ? hc : -1e30f;
        #pragma unroll
        for (int m = 1; m < 16; m <<= 1) mv = fmaxf(mv, __shfl_xor(mv, m, 16));
        const float ex = (g < 10) ? __expf(hc - mv) : 0.f;
        float den = ex;
        #pragma unroll
        for (int m = 1; m < 16; m <<= 1) den += __shfl_xor(den, m, 16);
        if (g < 10) smvS[g] = ex / den;
    }
    __syncthreads();

    // ---- phase C: 250 float4 stores, all 128 lanes (2 per lane) ----
    // out[pix, c, l]: invalid -> 0; class cl<10 -> one-hot; cl==10 -> smv[c].
    // float4 never crosses a c boundary (4 | 100); l0+3 <= 99 stays in chs.
    float* po = out + (size_t)pix * 1000;
    #pragma unroll
    for (int it = 0; it < 2; it++) {
        const int vi = t + it * 128;
        if (vi < 250) {
            const int idx = vi * 4;
            const int c   = idx / 100;       // 0..9, constant within float4
            const int l0  = idx - c * 100;   // multiple of 4
            const uchar4 c4 = *reinterpret_cast<const uchar4*>(chs + l0);
            const float sv = smvS[c];
            float4 v4;
            v4.x = (c4.x == 255) ? 0.f : ((c4.x < 10) ? ((c == c4.x) ? 1.f : 0.f) : sv);
            v4.y = (c4.y == 255) ? 0.f : ((c4.y < 10) ? ((c == c4.y) ? 1.f : 0.f) : sv);
            v4.z = (c4.z == 255) ? 0.f : ((c4.z < 10) ? ((c == c4.z) ? 1.f : 0.f) : sv);
            v4.w = (c4.w == 255) ? 0.f : ((c4.w < 10) ? ((c == c4.w) ? 1.f : 0.f) : sv);
            reinterpret_cast<float4*>(po)[vi] = v4;
        }
    }
}

extern "C" void kernel_launch(void* const* d_in, const int* in_sizes, int n_in,
                              void* d_out, int out_size, void* d_ws, size_t ws_size,
                              hipStream_t stream) {
    const float* x     = (const float*)d_in[0];
    const float* w_in  = (const float*)d_in[1];
    const float* w_out = (const float*)d_in[2];
    const float* w_ff1 = (const float*)d_in[3];
    const float* w_ff2 = (const float*)d_in[4];
    const float* ln1g  = (const float*)d_in[5];
    const float* ln2g  = (const float*)d_in[6];
    unsigned char* cm  = (unsigned char*)d_ws;   // 1800 bytes
    float* out = (float*)d_out;

    classify<<<(NPIX + 255) / 256, 256, 0, stream>>>(x, cm);
    emit<<<NPIX, 128, 0, stream>>>(w_in, w_out, w_ff1, w_ff2, ln1g, ln2g, cm, out);
}

// Round 7
// 73.615 us; speedup vs baseline: 1.5822x; 1.0441x over previous
//
#include <hip/hip_runtime.h>

// Problem constants (from reference)
#define NB   2
#define CC   10
#define HH   30
#define WW   30
#define PADR 4
#define DD   11           // C+1
#define NPIX (NB*HH*WW)   // 1800 pixels

// ---------------- Fused kernel: one block (128 thr) per pixel ---------------
// seq rows are one-hot -> per-channel softmax-attention reduces to a class-
// histogram weighted sum over tables E/EV; only the indicator-query (class
// 10) output is non-trivial (validated bit-exact R4-R6).
// Phase A: 100 threads decode the 9x9 window cells DIRECTLY from x
//          (branch-free 10-channel select; x is 72KB -> L2-resident) +
//          LDS-atomic histogram.
// Phase B: lanes 0-15 run the 11-dim pipeline wave-synchronously (shfl w16).
// Phase C: all 128 lanes emit 250 coalesced float4 (2 per lane).
__global__ __launch_bounds__(128) void pve_fused(
    const float* __restrict__ x,      // (N,C,H,W) one-hot
    const float* __restrict__ w_in,   // (33,11)
    const float* __restrict__ w_out,  // (11,11)
    const float* __restrict__ w_ff1,  // (1,11)
    const float* __restrict__ w_ff2,  // (11,1)
    const float* __restrict__ ln1g,   // (11,)
    const float* __restrict__ ln2g,   // (11,)
    float* __restrict__ out)          // (1800,10,100) f32
{
    __shared__ float E[121];    // exp(Q[d]*K[d][c]), Q = w_in[d][10]
    __shared__ float EV[121];   // E * V[d][c]
    __shared__ float WO[121];
    __shared__ float G1[11], G2[11], F1[11], F2[11];
    __shared__ int   cnt[11];
    __shared__ float smvS[10];
    __shared__ unsigned char chs[100];  // slot classes (255 = invalid)

    const int t = threadIdx.x;
    const int pix = blockIdx.x;
    const int n  = pix / (HH * WW);
    const int rm = pix % (HH * WW);
    const int i0 = rm / WW, j0 = rm % WW;

    // ---- tables ----
    if (t < 121) {
        const int d = t / 11, c = t % 11;
        const float Q = w_in[d * DD + 10];
        const float K = w_in[(DD + d) * DD + c];
        const float V = w_in[(2 * DD + d) * DD + c];
        const float e = __expf(Q * K);
        E[t] = e; EV[t] = e * V; WO[t] = w_out[t];
    }
    if (t < 11) {
        G1[t] = ln1g[t]; G2[t] = ln2g[t];
        F1[t] = w_ff1[t]; F2[t] = w_ff2[t];
        cnt[t] = 0;
    }
    __syncthreads();

    // ---- phase A: window decode + histogram (t < 100), l = ph*10+pw ----
    if (t < 100) {
        const int ph = t / 10, pw = t % 10;
        unsigned int c = 255;                 // invalid slot (ph>=9 || pw>=9)
        if (ph < 9 && pw < 9) {
            const int r  = i0 + ph - PADR;
            const int cc = j0 + pw - PADR;
            c = 10;                           // border indicator
            if (r >= 0 && r < HH && cc >= 0 && cc < WW) {
                // branch-free one-hot decode: 10 independent L2-hit loads
                const float* xp = x + n * CC * HH * WW + r * WW + cc;
                int cls = 10;
                #pragma unroll
                for (int k = CC - 1; k >= 0; k--) {
                    if (xp[k * HH * WW] > 0.5f) cls = k;
                }
                c = (unsigned int)cls;
            }
            atomicAdd(&cnt[c], 1);
        }
        chs[t] = (unsigned char)c;
    }
    __syncthreads();

    // ---- phase B: 11-dim pipeline on lanes 0-15 (wave-synchronous) ----
    if (t < 16) {
        const int g = t;
        const int d = (g < 11) ? g : 0;

        // attention via histogram: ao[d] = sum(cnt*EV)/sum(cnt*E)
        float s1 = 0.f, s2 = 0.f;
        #pragma unroll
        for (int c = 0; c < 11; c++) {
            const float cn = (float)cnt[c];
            s1 += cn * E[d * 11 + c];
            s2 += cn * EV[d * 11 + c];
        }
        const float ao = s2 / s1;

        // ao @ w_out.T + e_10 residual
        float h = 0.f;
        #pragma unroll
        for (int j = 0; j < 11; j++)
            h += WO[d * 11 + j] * __shfl(ao, j, 16);
        if (g == 10) h += 1.0f;
        if (g >= 11) h = 0.f;

        // LN1
        float s = h;
        #pragma unroll
        for (int m = 1; m < 16; m <<= 1) s += __shfl_xor(s, m, 16);
        float mean = s * (1.f / 11.f);
        float dv = (g < 11) ? (h - mean) : 0.f;
        float sq = dv * dv;
        #pragma unroll
        for (int m = 1; m < 16; m <<= 1) sq += __shfl_xor(sq, m, 16);
        const float hb = dv * rsqrtf(sq * (1.f / 11.f) + 1e-5f) * G1[d];

        // FF (scalar bottleneck) + residual
        float f = hb * F1[d];
        #pragma unroll
        for (int m = 1; m < 16; m <<= 1) f += __shfl_xor(f, m, 16);
        f = fmaxf(f, 0.f);
        float h2 = hb + f * F2[d];
        if (g >= 11) h2 = 0.f;

        // LN2
        s = h2;
        #pragma unroll
        for (int m = 1; m < 16; m <<= 1) s += __shfl_xor(s, m, 16);
        mean = s * (1.f / 11.f);
        dv = (g < 11) ? (h2 - mean) : 0.f;
        sq = dv * dv;
        #pragma unroll
        for (int m = 1; m < 16; m <<= 1) sq += __shfl_xor(sq, m, 16);
        const float hc = dv * rsqrtf(sq * (1.f / 11.f) + 1e-5f) * G2[d];

        // softmax over channels 0..9 (indicator query)
        float mv = (g < 10) ? hc : -1e30f;
        #pragma unroll
        for (int m = 1; m < 16; m <<= 1) mv = fmaxf(mv, __shfl_xor(mv, m, 16));
        const float ex = (g < 10) ? __expf(hc - mv) : 0.f;
        float den = ex;
        #pragma unroll
        for (int m = 1; m < 16; m <<= 1) den += __shfl_xor(den, m, 16);
        if (g < 10) smvS[g] = ex / den;
    }
    __syncthreads();

    // ---- phase C: 250 float4 stores, all 128 lanes (2 per lane) ----
    // out[pix, c, l]: invalid -> 0; class cl<10 -> one-hot; cl==10 -> smv[c].
    // float4 never crosses a c boundary (4 | 100); l0+3 <= 99 stays in chs.
    float* po = out + (size_t)pix * 1000;
    #pragma unroll
    for (int it = 0; it < 2; it++) {
        const int vi = t + it * 128;
        if (vi < 250) {
            const int idx = vi * 4;
            const int c   = idx / 100;       // 0..9, constant within float4
            const int l0  = idx - c * 100;   // multiple of 4
            const uchar4 c4 = *reinterpret_cast<const uchar4*>(chs + l0);
            const float sv = smvS[c];
            float4 v4;
            v4.x = (c4.x == 255) ? 0.f : ((c4.x < 10) ? ((c == c4.x) ? 1.f : 0.f) : sv);
            v4.y = (c4.y == 255) ? 0.f : ((c4.y < 10) ? ((c == c4.y) ? 1.f : 0.f) : sv);
            v4.z = (c4.z == 255) ? 0.f : ((c4.z < 10) ? ((c == c4.z) ? 1.f : 0.f) : sv);
            v4.w = (c4.w == 255) ? 0.f : ((c4.w < 10) ? ((c == c4.w) ? 1.f : 0.f) : sv);
            reinterpret_cast<float4*>(po)[vi] = v4;
        }
    }
}

extern "C" void kernel_launch(void* const* d_in, const int* in_sizes, int n_in,
                              void* d_out, int out_size, void* d_ws, size_t ws_size,
                              hipStream_t stream) {
    const float* x     = (const float*)d_in[0];
    const float* w_in  = (const float*)d_in[1];
    const float* w_out = (const float*)d_in[2];
    const float* w_ff1 = (const float*)d_in[3];
    const float* w_ff2 = (const float*)d_in[4];
    const float* ln1g  = (const float*)d_in[5];
    const float* ln2g  = (const float*)d_in[6];
    float* out = (float*)d_out;

    pve_fused<<<NPIX, 128, 0, stream>>>(x, w_in, w_out, w_ff1, w_ff2,
                                        ln1g, ln2g, out);
}

// Round 8
// 73.026 us; speedup vs baseline: 1.5950x; 1.0081x over previous
//
#include <hip/hip_runtime.h>

// Problem constants (from reference)
#define NB   2
#define CC   10
#define HH   30
#define WW   30
#define PADR 4
#define DD   11           // C+1
#define NPIX (NB*HH*WW)   // 1800 pixels

// ---------------- Fused kernel: one block (256 thr) per pixel ---------------
// seq rows are one-hot -> per-channel softmax-attention reduces to a class-
// histogram weighted sum over tables E/EV; only the indicator-query (class
// 10) output is non-trivial (validated bit-exact R4-R7).
//   waves 0-1 (t<128):  build E/EV/WO/G/F tables          \ overlapped
//   wave  2  (128-191): window decode + packed histogram  /  (independent)
//   barrier; wave 0 lanes 0-15: 11-dim pipeline (shfl w16, volatile-LDS
//   broadcast for the w_out matvec); barrier; 250 lanes store one float4 each.
__global__ __launch_bounds__(256) void pve_fused(
    const float* __restrict__ x,      // (N,C,H,W) one-hot
    const float* __restrict__ w_in,   // (33,11)
    const float* __restrict__ w_out,  // (11,11)
    const float* __restrict__ w_ff1,  // (1,11)
    const float* __restrict__ w_ff2,  // (11,1)
    const float* __restrict__ ln1g,   // (11,)
    const float* __restrict__ ln2g,   // (11,)
    float* __restrict__ out)          // (1800,10,100) f32
{
    __shared__ float E[121];    // exp(Q[d]*K[d][c]), Q = w_in[d][10]
    __shared__ float EV[121];   // E * V[d][c]
    __shared__ float WO[121];
    __shared__ float G1[11], G2[11], F1[11], F2[11];
    __shared__ float cntf[11];
    __shared__ float smvS[10];
    volatile __shared__ float aoS[16];  // wave-sync broadcast (wave 0 only)
    __shared__ unsigned char chs[100];  // slot classes (255 = invalid)

    const int t = threadIdx.x;
    const int pix = blockIdx.x;
    const int n  = pix / (HH * WW);
    const int rm = pix % (HH * WW);
    const int i0 = rm / WW, j0 = rm % WW;

    // ---- waves 0-1: tables ----
    if (t < 121) {
        const int d = t / 11, c = t % 11;
        const float Q = w_in[d * DD + 10];
        const float K = w_in[(DD + d) * DD + c];
        const float V = w_in[(2 * DD + d) * DD + c];
        const float e = __expf(Q * K);
        E[t] = e; EV[t] = e * V; WO[t] = w_out[t];
    }
    if (t < 11) {
        G1[t] = ln1g[t]; G2[t] = ln2g[t];
        F1[t] = w_ff1[t]; F2[t] = w_ff2[t];
    }

    // ---- wave 2: window decode + byte-packed histogram (no atomics) ----
    if (t >= 128 && t < 192) {
        const int lane = t - 128;          // 0..63
        unsigned int pk0 = 0, pk1 = 0, pk2 = 0;  // classes 0-3 / 4-7 / 8-10
        for (int l = lane; l < 100; l += 64) {
            const int ph = l / 10, pw = l % 10;
            unsigned int c = 255;          // invalid slot (ph>=9 || pw>=9)
            if (ph < 9 && pw < 9) {
                const int r  = i0 + ph - PADR;
                const int cc = j0 + pw - PADR;
                c = 10;                    // border indicator
                if (r >= 0 && r < HH && cc >= 0 && cc < WW) {
                    // branch-free one-hot decode: 10 independent L2-hit loads
                    const float* xp = x + n * CC * HH * WW + r * WW + cc;
                    int cls = 10;
                    #pragma unroll
                    for (int k = CC - 1; k >= 0; k--) {
                        if (xp[k * HH * WW] > 0.5f) cls = k;
                    }
                    c = (unsigned int)cls;
                }
                const unsigned int inc = 1u << ((c & 3) * 8);
                if (c < 4) pk0 += inc; else if (c < 8) pk1 += inc; else pk2 += inc;
            }
            chs[l] = (unsigned char)c;
        }
        // 6-stage xor reduce across the wave (counts <= 81 fit in a byte)
        #pragma unroll
        for (int m = 1; m < 64; m <<= 1) {
            pk0 += __shfl_xor(pk0, m, 64);
            pk1 += __shfl_xor(pk1, m, 64);
            pk2 += __shfl_xor(pk2, m, 64);
        }
        if (lane < 11) {
            const unsigned int pk = (lane < 4) ? pk0 : ((lane < 8) ? pk1 : pk2);
            cntf[lane] = (float)((pk >> ((lane & 3) * 8)) & 0xFFu);
        }
    }
    __syncthreads();

    // ---- wave 0 lanes 0-15: 11-dim pipeline (wave-synchronous) ----
    if (t < 16) {
        const int g = t;
        const int d = (g < 11) ? g : 0;

        // attention via histogram: ao[d] = sum(cnt*EV)/sum(cnt*E)
        float s1 = 0.f, s2 = 0.f;
        #pragma unroll
        for (int c = 0; c < 11; c++) {
            const float cn = cntf[c];
            s1 += cn * E[d * 11 + c];
            s2 += cn * EV[d * 11 + c];
        }
        const float ao = s2 / s1;

        // broadcast ao via LDS (in-order DS pipe within a wave; volatile
        // stops compiler reordering) -- replaces 11 dependent shfls
        aoS[g] = ao;
        float h = 0.f;
        #pragma unroll
        for (int j = 0; j < 11; j++)
            h += WO[d * 11 + j] * aoS[j];
        if (g == 10) h += 1.0f;
        if (g >= 11) h = 0.f;

        // LN1
        float s = h;
        #pragma unroll
        for (int m = 1; m < 16; m <<= 1) s += __shfl_xor(s, m, 16);
        float mean = s * (1.f / 11.f);
        float dv = (g < 11) ? (h - mean) : 0.f;
        float sq = dv * dv;
        #pragma unroll
        for (int m = 1; m < 16; m <<= 1) sq += __shfl_xor(sq, m, 16);
        const float hb = dv * rsqrtf(sq * (1.f / 11.f) + 1e-5f) * G1[d];

        // FF (scalar bottleneck) + residual
        float f = hb * F1[d];
        #pragma unroll
        for (int m = 1; m < 16; m <<= 1) f += __shfl_xor(f, m, 16);
        f = fmaxf(f, 0.f);
        float h2 = hb + f * F2[d];
        if (g >= 11) h2 = 0.f;

        // LN2
        s = h2;
        #pragma unroll
        for (int m = 1; m < 16; m <<= 1) s += __shfl_xor(s, m, 16);
        mean = s * (1.f / 11.f);
        dv = (g < 11) ? (h2 - mean) : 0.f;
        sq = dv * dv;
        #pragma unroll
        for (int m = 1; m < 16; m <<= 1) sq += __shfl_xor(sq, m, 16);
        const float hc = dv * rsqrtf(sq * (1.f / 11.f) + 1e-5f) * G2[d];

        // softmax over channels 0..9 (indicator query)
        float mv = (g < 10) ? hc : -1e30f;
        #pragma unroll
        for (int m = 1; m < 16; m <<= 1) mv = fmaxf(mv, __shfl_xor(mv, m, 16));
        const float ex = (g < 10) ? __expf(hc - mv) : 0.f;
        float den = ex;
        #pragma unroll
        for (int m = 1; m < 16; m <<= 1) den += __shfl_xor(den, m, 16);
        if (g < 10) smvS[g] = ex / den;
    }
    __syncthreads();

    // ---- epilogue: 250 float4 stores, one per lane ----
    // out[pix, c, l]: invalid -> 0; class cl<10 -> one-hot; cl==10 -> smv[c].
    // float4 never crosses a c boundary (4 | 100); l0+3 <= 99 stays in chs.
    if (t < 250) {
        const int idx = t * 4;
        const int c   = idx / 100;       // 0..9, constant within float4
        const int l0  = idx - c * 100;   // multiple of 4
        const uchar4 c4 = *reinterpret_cast<const uchar4*>(chs + l0);
        const float sv = smvS[c];
        float4 v4;
        v4.x = (c4.x == 255) ? 0.f : ((c4.x < 10) ? ((c == c4.x) ? 1.f : 0.f) : sv);
        v4.y = (c4.y == 255) ? 0.f : ((c4.y < 10) ? ((c == c4.y) ? 1.f : 0.f) : sv);
        v4.z = (c4.z == 255) ? 0.f : ((c4.z < 10) ? ((c == c4.z) ? 1.f : 0.f) : sv);
        v4.w = (c4.w == 255) ? 0.f : ((c4.w < 10) ? ((c == c4.w) ? 1.f : 0.f) : sv);
        reinterpret_cast<float4*>(out + (size_t)pix * 1000)[t] = v4;
    }
}

extern "C" void kernel_launch(void* const* d_in, const int* in_sizes, int n_in,
                              void* d_out, int out_size, void* d_ws, size_t ws_size,
                              hipStream_t stream) {
    const float* x     = (const float*)d_in[0];
    const float* w_in  = (const float*)d_in[1];
    const float* w_out = (const float*)d_in[2];
    const float* w_ff1 = (const float*)d_in[3];
    const float* w_ff2 = (const float*)d_in[4];
    const float* ln1g  = (const float*)d_in[5];
    const float* ln2g  = (const float*)d_in[6];
    float* out = (float*)d_out;

    pve_fused<<<NPIX, 256, 0, stream>>>(x, w_in, w_out, w_ff1, w_ff2,
                                        ln1g, ln2g, out);
}